// Round 6
// baseline (19.313 us; speedup 1.0000x reference)
//
#include <hip/hip_runtime.h>
#include <math.h>

namespace {
constexpr int kN = 1024;   // variable nodes
constexpr int kE = 3072;   // edges
constexpr int kB = 128;    // batch
constexpr float kClip = 0.999999f;
}

#define RCP(x) __builtin_amdgcn_rcpf(x)

// One wave per edge-row of vn2cn_mask [E,E], scanning only columns > row
// (upper triangle). The minimum edge of each 6-edge check group sees all 5
// partners above the diagonal (wave-uniform count == 5); it then writes, for
// ALL SIX group members:
//   part[e]: 5 partner-EDGE indices, 12b each (bits 0..59)
//   pvn[e] : 5 partner-VN indices (=edge/3), 10b each (bits 0..49), plus
//            4 dedup-include flags (bits 50..53) for partners 1..4 — flag j
//            set iff vn_j not among vn_0..vn_{j-1} (first_mask dedup,
//            ascending-edge order).
__global__ __launch_bounds__(256) void extract_partners_kernel(
    const uint4* __restrict__ mask, unsigned long long* __restrict__ part,
    unsigned long long* __restrict__ pvn) {
  __shared__ int slots[4][8];
  const int wave = threadIdx.x >> 6, lane = threadIdx.x & 63;
  const int row = blockIdx.x * 4 + wave;
  const uint4* rp = mask + (size_t)row * (kE / 4);
  const int it0 = (row + 1) >> 8;   // first 256-col chunk intersecting (row, E)

  // Prefetch (predicated, unrolled -> all loads outstanding together).
  uint4 vals[12];
#pragma unroll
  for (int it = 0; it < 12; ++it)
    if (it >= it0) vals[it] = rp[it * 64 + lane];

  const unsigned long long lt = (1ULL << lane) - 1ULL;
  int cnt = 0;
#pragma unroll
  for (int it = 0; it < 12; ++it) {
    if (it < it0) continue;
    uint4 v = vals[it];
    const int idx = it * 256 + lane * 4;  // float column of v.x
    const bool b0 = (v.x != 0u) & (idx + 0 > row);
    const bool b1 = (v.y != 0u) & (idx + 1 > row);
    const bool b2 = (v.z != 0u) & (idx + 2 > row);
    const bool b3 = (v.w != 0u) & (idx + 3 > row);
    unsigned long long m0 = __ballot(b0);
    unsigned long long m1 = __ballot(b1);
    unsigned long long m2 = __ballot(b2);
    unsigned long long m3 = __ballot(b3);
    int before = cnt + __popcll(m0 & lt) + __popcll(m1 & lt) +
                 __popcll(m2 & lt) + __popcll(m3 & lt);
    int own = 0;
    if (b0) slots[wave][min(before + own, 7)] = idx + 0;
    own += (int)((m0 >> lane) & 1ULL);
    if (b1) slots[wave][min(before + own, 7)] = idx + 1;
    own += (int)((m1 >> lane) & 1ULL);
    if (b2) slots[wave][min(before + own, 7)] = idx + 2;
    own += (int)((m2 >> lane) & 1ULL);
    if (b3) slots[wave][min(before + own, 7)] = idx + 3;
    cnt += __popcll(m0) + __popcll(m1) + __popcll(m2) + __popcll(m3);
  }
  __syncthreads();
  // cnt is wave-uniform; ==5 iff this row is its check group's minimum edge.
  if (cnt == 5 && lane < 6) {
    int g[6];
    g[0] = row;
#pragma unroll
    for (int i = 0; i < 5; ++i) g[i + 1] = slots[wave][i];  // ascending
    unsigned long long pk = 0, pw = 0;
    int pv[5];
    int sh = 0, k = 0;
#pragma unroll
    for (int i = 0; i < 6; ++i)
      if (i != lane) {
        pk |= (unsigned long long)(g[i] & 0xFFF) << sh;
        pv[k] = g[i] / 3;
        pw |= (unsigned long long)(pv[k] & 0x3FF) << (10 * k);
        sh += 12;
        ++k;
      }
    // dedup flags for partners 1..4 (bit 50+j-1): include iff new VN
#pragma unroll
    for (int j = 1; j < 5; ++j) {
      bool dup = false;
#pragma unroll
      for (int m = 0; m < 4; ++m)
        if (m < j) dup = dup || (pv[j] == pv[m]);
      if (!dup) pw |= 1ULL << (49 + j);
    }
    part[g[lane]] = pk;
    pvn[g[lane]] = pw;
  }
}

// One block (1024 threads) per batch item. Thread tid owns edges 3tid+{0,1,2}
// (exactly the edges of VN tid), so CN outputs y0..y2 stay in registers and
// only the tanh-domain edge messages tmE round-trip through LDS
// (double-buffered -> ONE barrier per iteration).
// y-domain algebra (y = clipped tanh message):
//   VN edge update: tanh(0.5(llr+m_a+m_b)) = (n-d)/(n+d),
//     n = e^llr (1+y_a)(1+y_b), d = (1-y_a)(1-y_b)
//   output: sigmoid(llr+m0+m1+m2) = N/(N+D),
//     N = e^llr (1+y0)(1+y1)(1+y2), D = (1-y0)(1-y1)(1-y2)
// Only transcendental: one __expf per VN at init. CN phase has zero rcp.
__global__ __launch_bounds__(1024) void bp_kernel(
    const float* __restrict__ x, const unsigned long long* __restrict__ part,
    const unsigned long long* __restrict__ pvn, float* __restrict__ out) {
  __shared__ float tmV[kN];      // first-layer per-VN tanh values
  __shared__ float tmE[2][kE];   // edge messages, double-buffered
  const int b = blockIdx.x;
  const int tid = threadIdx.x;

  // Partner-edge indices for the 3 owned edges -> registers (all static idx).
  int idx[3][5];
  unsigned long long pw[3];
#pragma unroll
  for (int i = 0; i < 3; ++i) {
    const unsigned long long pk = part[3 * tid + i];
#pragma unroll
    for (int j = 0; j < 5; ++j) idx[i][j] = (int)((pk >> (12 * j)) & 0xFFF);
    pw[i] = pvn[3 * tid + i];
  }

  const float l = x[(size_t)b * kN + tid];
  const float E = __expf(l);
  tmV[tid] = (E - 1.0f) * RCP(E + 1.0f);
  __syncthreads();                                   // barrier 1

  float y[3];
  // fc0: CN product over DISTINCT partner VNs — VN ids + dedup flags were
  // precomputed in extract; 5 LDS reads + 4 flag-selected muls.
#pragma unroll
  for (int i = 0; i < 3; ++i) {
    const unsigned long long w = pw[i];
    const int v0 = (int)(w & 0x3FF), v1 = (int)((w >> 10) & 0x3FF),
              v2 = (int)((w >> 20) & 0x3FF), v3 = (int)((w >> 30) & 0x3FF),
              v4 = (int)((w >> 40) & 0x3FF);
    float prod = tmV[v0];
    prod *= ((w >> 50) & 1ULL) ? tmV[v1] : 1.0f;
    prod *= ((w >> 51) & 1ULL) ? tmV[v2] : 1.0f;
    prod *= ((w >> 52) & 1ULL) ? tmV[v3] : 1.0f;
    prod *= ((w >> 53) & 1ULL) ? tmV[v4] : 1.0f;
    y[i] = fminf(fmaxf(prod, -kClip), kClip);
  }

  float* ob = out + (size_t)b * kN + tid;

  // OUT(slot) + VN update of the 3 owned edges into wbuf.
#define OUT_VN(slot, wbuf)                                                 \
  {                                                                        \
    const float a0 = 1.0f + y[0], a1 = 1.0f + y[1], a2 = 1.0f + y[2];      \
    const float s0 = 1.0f - y[0], s1 = 1.0f - y[1], s2 = 1.0f - y[2];      \
    const float Nn = E * a0 * a1 * a2;                                     \
    const float Dd = s0 * s1 * s2;                                         \
    ob[(size_t)(slot) * kB * kN] = Nn * RCP(Nn + Dd);                      \
    const float n0 = E * a1 * a2, d0 = s1 * s2;                            \
    const float n1 = E * a0 * a2, d1 = s0 * s2;                            \
    const float n2 = E * a0 * a1, d2 = s0 * s1;                            \
    (wbuf)[3 * tid + 0] = (n0 - d0) * RCP(n0 + d0);                        \
    (wbuf)[3 * tid + 1] = (n1 - d1) * RCP(n1 + d1);                        \
    (wbuf)[3 * tid + 2] = (n2 - d2) * RCP(n2 + d2);                        \
  }

  // CN product over the 5 partner edges from rbuf.
#define CN(rbuf)                                                           \
  {                                                                        \
    _Pragma("unroll") for (int i = 0; i < 3; ++i) {                        \
      const float p = (rbuf)[idx[i][0]] * (rbuf)[idx[i][1]] *              \
                      (rbuf)[idx[i][2]] * (rbuf)[idx[i][3]] *              \
                      (rbuf)[idx[i][4]];                                   \
      y[i] = fminf(fmaxf(p, -kClip), kClip);                               \
    }                                                                      \
  }

  OUT_VN(4, tmE[0]);   // out1
  __syncthreads();     // barrier 2
  CN(tmE[0]);
  OUT_VN(3, tmE[1]);   // out2
  __syncthreads();     // barrier 3
  CN(tmE[1]);
  OUT_VN(2, tmE[0]);   // out3
  __syncthreads();     // barrier 4
  CN(tmE[0]);
  OUT_VN(1, tmE[1]);   // out4
  __syncthreads();     // barrier 5
  CN(tmE[1]);
  // out5 -> slot 0 (no further VN update needed)
  {
    const float a0 = 1.0f + y[0], a1 = 1.0f + y[1], a2 = 1.0f + y[2];
    const float s0 = 1.0f - y[0], s1 = 1.0f - y[1], s2 = 1.0f - y[2];
    const float Nn = E * a0 * a1 * a2;
    const float Dd = s0 * s1 * s2;
    ob[0] = Nn * RCP(Nn + Dd);
  }
#undef OUT_VN
#undef CN
}

extern "C" void kernel_launch(void* const* d_in, const int* in_sizes, int n_in,
                              void* d_out, int out_size, void* d_ws, size_t ws_size,
                              hipStream_t stream) {
  const float* x = (const float*)d_in[0];       // [128,1024] channel LLRs
  const float* vn2cn = (const float*)d_in[3];   // [3072,3072] same-check mask
  unsigned long long* part = (unsigned long long*)d_ws;          // [3072]
  unsigned long long* pvn = (unsigned long long*)d_ws + kE;      // [3072]
  float* out = (float*)d_out;                    // [5,128,1024] f32

  hipLaunchKernelGGL(extract_partners_kernel, dim3(kE / 4), dim3(256), 0, stream,
                     (const uint4*)vn2cn, part, pvn);
  hipLaunchKernelGGL(bp_kernel, dim3(kB), dim3(1024), 0, stream, x, part, pvn, out);
}

// Round 7
// 19.218 us; speedup vs baseline: 1.0049x; 1.0049x over previous
//
#include <hip/hip_runtime.h>
#include <math.h>

namespace {
constexpr int kN = 1024;   // variable nodes
constexpr int kE = 3072;   // edges
constexpr int kB = 128;    // batch
constexpr float kClip = 0.999999f;
}

#define RCP(x) __builtin_amdgcn_rcpf(x)

// One wave per edge-row of vn2cn_mask [E,E], scanning only columns > row
// (upper triangle). The minimum edge of each 6-edge check group sees all 5
// partners above the diagonal (wave-uniform count == 5); it then writes the
// packed 5x12-bit partner list for ALL SIX group members. Each part[] entry
// is written exactly once. Halves mask bytes read vs a full scan.
__global__ __launch_bounds__(256) void extract_partners_kernel(
    const uint4* __restrict__ mask, unsigned long long* __restrict__ part) {
  __shared__ int slots[4][8];
  const int wave = threadIdx.x >> 6, lane = threadIdx.x & 63;
  const int row = blockIdx.x * 4 + wave;
  const uint4* rp = mask + (size_t)row * (kE / 4);
  const int it0 = (row + 1) >> 8;   // first 256-col chunk intersecting (row, E)

  // Prefetch (predicated, unrolled -> all loads outstanding together).
  uint4 vals[12];
#pragma unroll
  for (int it = 0; it < 12; ++it)
    if (it >= it0) vals[it] = rp[it * 64 + lane];

  const unsigned long long lt = (1ULL << lane) - 1ULL;
  int cnt = 0;
#pragma unroll
  for (int it = 0; it < 12; ++it) {
    if (it < it0) continue;
    uint4 v = vals[it];
    const int idx = it * 256 + lane * 4;  // float column of v.x
    const bool b0 = (v.x != 0u) & (idx + 0 > row);
    const bool b1 = (v.y != 0u) & (idx + 1 > row);
    const bool b2 = (v.z != 0u) & (idx + 2 > row);
    const bool b3 = (v.w != 0u) & (idx + 3 > row);
    unsigned long long m0 = __ballot(b0);
    unsigned long long m1 = __ballot(b1);
    unsigned long long m2 = __ballot(b2);
    unsigned long long m3 = __ballot(b3);
    int before = cnt + __popcll(m0 & lt) + __popcll(m1 & lt) +
                 __popcll(m2 & lt) + __popcll(m3 & lt);
    int own = 0;
    if (b0) slots[wave][min(before + own, 7)] = idx + 0;
    own += (int)((m0 >> lane) & 1ULL);
    if (b1) slots[wave][min(before + own, 7)] = idx + 1;
    own += (int)((m1 >> lane) & 1ULL);
    if (b2) slots[wave][min(before + own, 7)] = idx + 2;
    own += (int)((m2 >> lane) & 1ULL);
    if (b3) slots[wave][min(before + own, 7)] = idx + 3;
    cnt += __popcll(m0) + __popcll(m1) + __popcll(m2) + __popcll(m3);
  }
  __syncthreads();
  // cnt is wave-uniform; ==5 iff this row is its check group's minimum edge.
  if (cnt == 5 && lane < 6) {
    int g[6];
    g[0] = row;
#pragma unroll
    for (int i = 0; i < 5; ++i) g[i + 1] = slots[wave][i];  // ascending
    unsigned long long pk = 0;
    int sh = 0;
#pragma unroll
    for (int i = 0; i < 6; ++i)
      if (i != lane) {
        pk |= (unsigned long long)(g[i] & 0xFFF) << sh;
        sh += 12;
      }
    part[g[lane]] = pk;
  }
}

// 256 blocks (2 per batch item's worth of waves is gone — now ONE block per
// batch item is split differently): one block of 512 threads per batch item
// would leave 128 CUs idle, so we use 256 blocks x 512 threads with TWO VNs
// per thread: block b owns batch item b>>1? No — each block must hold the
// whole edge state. Instead: one block per batch item, 512 threads, each
// thread owns VNs {tid, tid+512} (6 edges) -> grid 128... To fill all 256
// CUs we instead launch 256 blocks where block q handles batch item q>>1 is
// wrong too. Final design: 256 blocks, each handling ONE batch item with 512
// threads x 2 VNs, batch items 0..127 on blocks 0..127 and repeated work is
// avoided by b = blockIdx.x (grid IS 128)... — see launch: grid is 256 with
// b = blockIdx.x >> 1 impossible without splitting state.
//
// Actual scheme (simple + correct): grid = 256 blocks, 512 threads; block
// pair (2q, 2q+1) BOTH compute batch item q's edge state (identical LDS
// work), but each writes only half of the 5 outputs: block 2q writes slots
// {4,3}, wait — that halves nothing.
//
// Chosen: block = one batch item, 512 threads, 2 VNs/thread, grid 128.
// Per-CU work halves vs 1024-thread version only through wave count (16->8)
// on the SAME 128 CUs — so instead we keep 1024 threads but launch the
// batch SPLIT: grid 256, block 512 threads, block b computes batch item
// b & 127... duplicates. Simplest true win: 2 batch items per block is the
// opposite direction.
//
// => Decision: 512 threads/block, TWO blocks per batch item sharing nothing:
// block 2q+h computes the FULL message recursion for batch item q in its own
// LDS (duplicated compute, which is cheap) and writes output slots
// h ? {4,2,0} : {3,1}. Output-write traffic is split; compute is duplicated
// across 2 CUs; the serial VALU path per CU is identical to the 512-thread
// version but all 256 CUs are active and each CU writes half the outputs.
__global__ __launch_bounds__(512) void bp_kernel(
    const float* __restrict__ x, const unsigned long long* __restrict__ part,
    float* __restrict__ out) {
  __shared__ float tmV[kN];      // first-layer per-VN tanh values
  __shared__ float tmE[2][kE];   // edge messages, double-buffered
  const int b = blockIdx.x >> 1;       // batch item
  const int h = blockIdx.x & 1;        // output-half selector
  const int tid = threadIdx.x;

  int idx[2][3][5];
  float E[2];
#pragma unroll
  for (int u = 0; u < 2; ++u) {
    const int v = tid + u * 512;
#pragma unroll
    for (int i = 0; i < 3; ++i) {
      const unsigned long long pk = part[3 * v + i];
#pragma unroll
      for (int j = 0; j < 5; ++j)
        idx[u][i][j] = (int)((pk >> (12 * j)) & 0xFFF);
    }
    const float l = x[(size_t)b * kN + v];
    E[u] = __expf(l);
    tmV[v] = (E[u] - 1.0f) * RCP(E[u] + 1.0f);
  }
  __syncthreads();                                   // barrier 1

  float y[2][3];
  // fc0: CN product over DISTINCT partner VNs (first_mask dedups repeats)
#pragma unroll
  for (int u = 0; u < 2; ++u)
#pragma unroll
    for (int i = 0; i < 3; ++i) {
      const int q0 = idx[u][i][0] / 3, q1 = idx[u][i][1] / 3,
                q2 = idx[u][i][2] / 3, q3 = idx[u][i][3] / 3,
                q4 = idx[u][i][4] / 3;
      float prod = tmV[q0];
      const float f1 = tmV[q1], f2 = tmV[q2], f3 = tmV[q3], f4 = tmV[q4];
      prod *= (q1 == q0) ? 1.0f : f1;
      prod *= (q2 == q0 || q2 == q1) ? 1.0f : f2;
      prod *= (q3 == q0 || q3 == q1 || q3 == q2) ? 1.0f : f3;
      prod *= (q4 == q0 || q4 == q1 || q4 == q2 || q4 == q3) ? 1.0f : f4;
      y[u][i] = fminf(fmaxf(prod, -kClip), kClip);
    }

  // OUT(slot, doit) + VN update of the 6 owned edges into wbuf.
#define OUT_VN(slot, doit, wbuf)                                           \
  _Pragma("unroll") for (int u = 0; u < 2; ++u) {                          \
    const float a0 = 1.0f + y[u][0], a1 = 1.0f + y[u][1],                  \
                a2 = 1.0f + y[u][2];                                       \
    const float s0 = 1.0f - y[u][0], s1 = 1.0f - y[u][1],                  \
                s2 = 1.0f - y[u][2];                                       \
    const float Ee = E[u];                                                 \
    if (doit) {                                                            \
      const float Nn = Ee * a0 * a1 * a2;                                  \
      const float Dd = s0 * s1 * s2;                                       \
      out[(size_t)(slot) * kB * kN + (size_t)b * kN + tid + u * 512] =     \
          Nn * RCP(Nn + Dd);                                               \
    }                                                                      \
    const int e0 = 3 * (tid + u * 512);                                    \
    const float n0 = Ee * a1 * a2, d0 = s1 * s2;                           \
    const float n1 = Ee * a0 * a2, d1 = s0 * s2;                           \
    const float n2 = Ee * a0 * a1, d2 = s0 * s1;                           \
    (wbuf)[e0 + 0] = (n0 - d0) * RCP(n0 + d0);                             \
    (wbuf)[e0 + 1] = (n1 - d1) * RCP(n1 + d1);                             \
    (wbuf)[e0 + 2] = (n2 - d2) * RCP(n2 + d2);                             \
  }

  // CN product over the 5 partner edges from rbuf.
#define CN(rbuf)                                                           \
  _Pragma("unroll") for (int u = 0; u < 2; ++u)                            \
      _Pragma("unroll") for (int i = 0; i < 3; ++i) {                      \
    const float p = (rbuf)[idx[u][i][0]] * (rbuf)[idx[u][i][1]] *          \
                    (rbuf)[idx[u][i][2]] * (rbuf)[idx[u][i][3]] *          \
                    (rbuf)[idx[u][i][4]];                                  \
    y[u][i] = fminf(fmaxf(p, -kClip), kClip);                              \
  }

  OUT_VN(4, h == 1, tmE[0]);   // out1
  __syncthreads();             // barrier 2
  CN(tmE[0]);
  OUT_VN(3, h == 0, tmE[1]);   // out2
  __syncthreads();             // barrier 3
  CN(tmE[1]);
  OUT_VN(2, h == 1, tmE[0]);   // out3
  __syncthreads();             // barrier 4
  CN(tmE[0]);
  OUT_VN(1, h == 0, tmE[1]);   // out4
  __syncthreads();             // barrier 5
  CN(tmE[1]);
  // out5 -> slot 0 (no further VN update needed)
  if (h == 1) {
#pragma unroll
    for (int u = 0; u < 2; ++u) {
      const float a0 = 1.0f + y[u][0], a1 = 1.0f + y[u][1],
                  a2 = 1.0f + y[u][2];
      const float s0 = 1.0f - y[u][0], s1 = 1.0f - y[u][1],
                  s2 = 1.0f - y[u][2];
      const float Nn = E[u] * a0 * a1 * a2;
      const float Dd = s0 * s1 * s2;
      out[(size_t)b * kN + tid + u * 512] = Nn * RCP(Nn + Dd);
    }
  }
#undef OUT_VN
#undef CN
}

extern "C" void kernel_launch(void* const* d_in, const int* in_sizes, int n_in,
                              void* d_out, int out_size, void* d_ws, size_t ws_size,
                              hipStream_t stream) {
  const float* x = (const float*)d_in[0];       // [128,1024] channel LLRs
  const float* vn2cn = (const float*)d_in[3];   // [3072,3072] same-check mask
  unsigned long long* part = (unsigned long long*)d_ws;  // [3072] packed partners
  float* out = (float*)d_out;                    // [5,128,1024] f32

  hipLaunchKernelGGL(extract_partners_kernel, dim3(kE / 4), dim3(256), 0, stream,
                     (const uint4*)vn2cn, part);
  hipLaunchKernelGGL(bp_kernel, dim3(2 * kB), dim3(512), 0, stream, x, part, out);
}

// Round 8
// 17.944 us; speedup vs baseline: 1.0763x; 1.0710x over previous
//
#include <hip/hip_runtime.h>
#include <math.h>

namespace {
constexpr int kN = 1024;   // variable nodes
constexpr int kE = 3072;   // edges
constexpr int kB = 128;    // batch
constexpr float kClip = 0.999999f;
}

#define RCP(x) __builtin_amdgcn_rcpf(x)

// One wave per edge-row of vn2cn_mask [E,E], scanning only columns > row
// (upper triangle). The minimum edge of each 6-edge check group sees all 5
// partners above the diagonal (wave-uniform count == 5); it then writes the
// packed 5x12-bit partner list for ALL SIX group members. Each part[] entry
// is written exactly once. Halves mask bytes read vs a full scan.
__global__ __launch_bounds__(256) void extract_partners_kernel(
    const uint4* __restrict__ mask, unsigned long long* __restrict__ part) {
  __shared__ int slots[4][8];
  const int wave = threadIdx.x >> 6, lane = threadIdx.x & 63;
  const int row = blockIdx.x * 4 + wave;
  const uint4* rp = mask + (size_t)row * (kE / 4);
  const int it0 = (row + 1) >> 8;   // first 256-col chunk intersecting (row, E)

  // Prefetch (predicated, unrolled -> all loads outstanding together).
  uint4 vals[12];
#pragma unroll
  for (int it = 0; it < 12; ++it)
    if (it >= it0) vals[it] = rp[it * 64 + lane];

  const unsigned long long lt = (1ULL << lane) - 1ULL;
  int cnt = 0;
#pragma unroll
  for (int it = 0; it < 12; ++it) {
    if (it < it0) continue;
    uint4 v = vals[it];
    const int idx = it * 256 + lane * 4;  // float column of v.x
    const bool b0 = (v.x != 0u) & (idx + 0 > row);
    const bool b1 = (v.y != 0u) & (idx + 1 > row);
    const bool b2 = (v.z != 0u) & (idx + 2 > row);
    const bool b3 = (v.w != 0u) & (idx + 3 > row);
    unsigned long long m0 = __ballot(b0);
    unsigned long long m1 = __ballot(b1);
    unsigned long long m2 = __ballot(b2);
    unsigned long long m3 = __ballot(b3);
    int before = cnt + __popcll(m0 & lt) + __popcll(m1 & lt) +
                 __popcll(m2 & lt) + __popcll(m3 & lt);
    int own = 0;
    if (b0) slots[wave][min(before + own, 7)] = idx + 0;
    own += (int)((m0 >> lane) & 1ULL);
    if (b1) slots[wave][min(before + own, 7)] = idx + 1;
    own += (int)((m1 >> lane) & 1ULL);
    if (b2) slots[wave][min(before + own, 7)] = idx + 2;
    own += (int)((m2 >> lane) & 1ULL);
    if (b3) slots[wave][min(before + own, 7)] = idx + 3;
    cnt += __popcll(m0) + __popcll(m1) + __popcll(m2) + __popcll(m3);
  }
  __syncthreads();
  // cnt is wave-uniform; ==5 iff this row is its check group's minimum edge.
  if (cnt == 5 && lane < 6) {
    int g[6];
    g[0] = row;
#pragma unroll
    for (int i = 0; i < 5; ++i) g[i + 1] = slots[wave][i];  // ascending
    unsigned long long pk = 0;
    int sh = 0;
#pragma unroll
    for (int i = 0; i < 6; ++i)
      if (i != lane) {
        pk |= (unsigned long long)(g[i] & 0xFFF) << sh;
        sh += 12;
      }
    part[g[lane]] = pk;
  }
}

// One block (1024 threads) per batch item. Thread tid owns edges 3tid+{0,1,2}
// (exactly the edges of VN tid), so CN outputs y0..y2 stay in registers and
// only the tanh-domain edge messages tmE round-trip through LDS
// (double-buffered -> ONE barrier per iteration).
// y-domain algebra (y = clipped tanh message):
//   VN edge update: tanh(0.5(llr+m_a+m_b)) = (n-d)/(n+d),
//     n = e^llr (1+y_a)(1+y_b), d = (1-y_a)(1-y_b)
//   output: sigmoid(llr+m0+m1+m2) = N/(N+D),
//     N = e^llr (1+y0)(1+y1)(1+y2), D = (1-y0)(1-y1)(1-y2)
// Only transcendental: one __expf per VN at init. CN phase has zero rcp.
__global__ __launch_bounds__(1024) void bp_kernel(
    const float* __restrict__ x, const unsigned long long* __restrict__ part,
    float* __restrict__ out) {
  __shared__ float tmV[kN];      // first-layer per-VN tanh values
  __shared__ float tmE[2][kE];   // edge messages, double-buffered
  const int b = blockIdx.x;
  const int tid = threadIdx.x;

  // Partner-edge indices for the 3 owned edges -> registers (all static idx).
  int idx[3][5];
#pragma unroll
  for (int i = 0; i < 3; ++i) {
    const unsigned long long pk = part[3 * tid + i];
#pragma unroll
    for (int j = 0; j < 5; ++j) idx[i][j] = (int)((pk >> (12 * j)) & 0xFFF);
  }

  const float l = x[(size_t)b * kN + tid];
  const float E = __expf(l);
  tmV[tid] = (E - 1.0f) * RCP(E + 1.0f);
  __syncthreads();                                   // barrier 1

  float y[3];
  // fc0: CN product over DISTINCT partner VNs (first_mask dedups repeats)
#pragma unroll
  for (int i = 0; i < 3; ++i) {
    const int q0 = idx[i][0] / 3, q1 = idx[i][1] / 3, q2 = idx[i][2] / 3,
              q3 = idx[i][3] / 3, q4 = idx[i][4] / 3;
    float prod = tmV[q0];
    const float f1 = tmV[q1], f2 = tmV[q2], f3 = tmV[q3], f4 = tmV[q4];
    prod *= (q1 == q0) ? 1.0f : f1;
    prod *= (q2 == q0 || q2 == q1) ? 1.0f : f2;
    prod *= (q3 == q0 || q3 == q1 || q3 == q2) ? 1.0f : f3;
    prod *= (q4 == q0 || q4 == q1 || q4 == q2 || q4 == q3) ? 1.0f : f4;
    y[i] = fminf(fmaxf(prod, -kClip), kClip);
  }

  float* ob = out + (size_t)b * kN + tid;

  // OUT(slot) + VN update of the 3 owned edges into wbuf.
#define OUT_VN(slot, wbuf)                                                 \
  {                                                                        \
    const float a0 = 1.0f + y[0], a1 = 1.0f + y[1], a2 = 1.0f + y[2];      \
    const float s0 = 1.0f - y[0], s1 = 1.0f - y[1], s2 = 1.0f - y[2];      \
    const float Nn = E * a0 * a1 * a2;                                     \
    const float Dd = s0 * s1 * s2;                                         \
    ob[(size_t)(slot) * kB * kN] = Nn * RCP(Nn + Dd);                      \
    const float n0 = E * a1 * a2, d0 = s1 * s2;                            \
    const float n1 = E * a0 * a2, d1 = s0 * s2;                            \
    const float n2 = E * a0 * a1, d2 = s0 * s1;                            \
    (wbuf)[3 * tid + 0] = (n0 - d0) * RCP(n0 + d0);                        \
    (wbuf)[3 * tid + 1] = (n1 - d1) * RCP(n1 + d1);                        \
    (wbuf)[3 * tid + 2] = (n2 - d2) * RCP(n2 + d2);                        \
  }

  // CN product over the 5 partner edges from rbuf.
#define CN(rbuf)                                                           \
  {                                                                        \
    _Pragma("unroll") for (int i = 0; i < 3; ++i) {                        \
      const float p = (rbuf)[idx[i][0]] * (rbuf)[idx[i][1]] *              \
                      (rbuf)[idx[i][2]] * (rbuf)[idx[i][3]] *              \
                      (rbuf)[idx[i][4]];                                   \
      y[i] = fminf(fmaxf(p, -kClip), kClip);                               \
    }                                                                      \
  }

  OUT_VN(4, tmE[0]);   // out1
  __syncthreads();     // barrier 2
  CN(tmE[0]);
  OUT_VN(3, tmE[1]);   // out2
  __syncthreads();     // barrier 3
  CN(tmE[1]);
  OUT_VN(2, tmE[0]);   // out3
  __syncthreads();     // barrier 4
  CN(tmE[0]);
  OUT_VN(1, tmE[1]);   // out4
  __syncthreads();     // barrier 5
  CN(tmE[1]);
  // out5 -> slot 0 (no further VN update needed)
  {
    const float a0 = 1.0f + y[0], a1 = 1.0f + y[1], a2 = 1.0f + y[2];
    const float s0 = 1.0f - y[0], s1 = 1.0f - y[1], s2 = 1.0f - y[2];
    const float Nn = E * a0 * a1 * a2;
    const float Dd = s0 * s1 * s2;
    ob[0] = Nn * RCP(Nn + Dd);
  }
#undef OUT_VN
#undef CN
}

extern "C" void kernel_launch(void* const* d_in, const int* in_sizes, int n_in,
                              void* d_out, int out_size, void* d_ws, size_t ws_size,
                              hipStream_t stream) {
  const float* x = (const float*)d_in[0];       // [128,1024] channel LLRs
  const float* vn2cn = (const float*)d_in[3];   // [3072,3072] same-check mask
  unsigned long long* part = (unsigned long long*)d_ws;  // [3072] packed partners
  float* out = (float*)d_out;                    // [5,128,1024] f32

  hipLaunchKernelGGL(extract_partners_kernel, dim3(kE / 4), dim3(256), 0, stream,
                     (const uint4*)vn2cn, part);
  hipLaunchKernelGGL(bp_kernel, dim3(kB), dim3(1024), 0, stream, x, part, out);
}